// Round 1
// baseline (192.417 us; speedup 1.0000x reference)
//
#include <hip/hip_runtime.h>
#include <hip/hip_bf16.h>

#define BB 2
#define NN 2048
#define CC 768
#define HH 12
#define DD 64
#define MM 4096
#define N3 2304

typedef __attribute__((ext_vector_type(8))) short bf16x8;
typedef __attribute__((ext_vector_type(4))) float f32x4;

__device__ __forceinline__ unsigned short f2bf(float f) {
    union { float f; unsigned u; } v; v.f = f;
    unsigned r = v.u + 0x7FFFu + ((v.u >> 16) & 1u);
    return (unsigned short)(r >> 16);
}

// loads elements [0..3] and [16..19] from p (bf16 A/B fragment k-pattern:
// e0-3 -> k = lg*4 + e, e4-7 -> k = 16 + lg*4 + (e-4))
__device__ __forceinline__ bf16x8 ld_frag(const unsigned short* p) {
    bf16x8 r;
    __builtin_memcpy(&r, p, 8);
    __builtin_memcpy((char*)&r + 8, p + 16, 8);
    return r;
}

__global__ void k_cvt(const float* __restrict__ s, unsigned short* __restrict__ d, int n4) {
    int i = blockIdx.x * blockDim.x + threadIdx.x;
    int st = gridDim.x * blockDim.x;
    for (; i < n4; i += st) {
        float4 v = ((const float4*)s)[i];
        ushort4 o;
        o.x = f2bf(v.x); o.y = f2bf(v.y); o.z = f2bf(v.z); o.w = f2bf(v.w);
        ((ushort4*)d)[i] = o;
    }
}

// ---------------- GEMM1: qkv = x @ W_qkv + b, fused RoPE ----------------
// grid (32, 36), block 256. Tile 128(M) x 64(N), BK=32.
// Each 64-col tile is exactly one (t, h): t=0 q, t=1 k, t=2 v.
__launch_bounds__(256)
__global__ void k_qkv(const unsigned short* __restrict__ xb,
                      const unsigned short* __restrict__ wb,
                      const float* __restrict__ bias,
                      const float* __restrict__ sinp,
                      const float* __restrict__ cosp,
                      unsigned short* __restrict__ qws,
                      unsigned short* __restrict__ kws,
                      unsigned short* __restrict__ vws) {
    __shared__ unsigned short As[128][40];   // [m][k], pad to 40 (80B rows, 16B-aligned)
    __shared__ unsigned short Bs[64][40];    // transposed: [j][k]
    const int tid = threadIdx.x;
    const int lane = tid & 63, w = tid >> 6;
    const int ql = lane & 15, lg = lane >> 4;
    const int row0 = blockIdx.x * 128;
    const int j0 = blockIdx.y * 64;

    f32x4 acc[2][4];
#pragma unroll
    for (int a = 0; a < 2; a++)
#pragma unroll
        for (int b = 0; b < 4; b++) acc[a][b] = f32x4{0.f, 0.f, 0.f, 0.f};

    const int ar = tid >> 1, ac = (tid & 1) * 16;
    const int bk = tid >> 3, bc = (tid & 7) * 8;

    for (int k0 = 0; k0 < CC; k0 += 32) {
        uint4 av0 = *(const uint4*)(xb + (size_t)(row0 + ar) * CC + k0 + ac);
        uint4 av1 = *(const uint4*)(xb + (size_t)(row0 + ar) * CC + k0 + ac + 8);
        uint4 bv  = *(const uint4*)(wb + (size_t)(k0 + bk) * N3 + j0 + bc);
        *(uint4*)&As[ar][ac]     = av0;
        *(uint4*)&As[ar][ac + 8] = av1;
        const unsigned short* pb = (const unsigned short*)&bv;
#pragma unroll
        for (int i = 0; i < 8; i++) Bs[bc + i][bk] = pb[i];
        __syncthreads();

        bf16x8 af[2], bfr[4];
#pragma unroll
        for (int fr = 0; fr < 2; fr++) af[fr] = ld_frag(&As[w * 32 + fr * 16 + ql][lg * 4]);
#pragma unroll
        for (int fn = 0; fn < 4; fn++) bfr[fn] = ld_frag(&Bs[fn * 16 + ql][lg * 4]);
#pragma unroll
        for (int fr = 0; fr < 2; fr++)
#pragma unroll
            for (int fn = 0; fn < 4; fn++)
                acc[fr][fn] = __builtin_amdgcn_mfma_f32_16x16x32_bf16(af[fr], bfr[fn], acc[fr][fn], 0, 0, 0);
        __syncthreads();
    }

    // epilogue: bias, rope, store. C/D layout: row=(lg*4+reg), col=ql (m89-verified)
    float vals[2][4][4];
#pragma unroll
    for (int fr = 0; fr < 2; fr++)
#pragma unroll
        for (int fn = 0; fn < 4; fn++) {
            float bj = bias[j0 + fn * 16 + ql];
#pragma unroll
            for (int r = 0; r < 4; r++) vals[fr][fn][r] = acc[fr][fn][r] + bj;
        }
    const int t = j0 / CC;
    const int h = (j0 % CC) >> 6;
    if (t < 2) {
        unsigned short* outp = (t == 0) ? qws : kws;
#pragma unroll
        for (int fr = 0; fr < 2; fr++)
#pragma unroll
            for (int r = 0; r < 4; r++) {
                int m = row0 + w * 32 + fr * 16 + lg * 4 + r;
                int b = m >> 11, n = m & (NN - 1);
#pragma unroll
                for (int fn = 0; fn < 4; fn++) {
                    int d = fn * 16 + ql;
                    float cv = cosp[n * DD + d], sv = sinp[n * DD + d];
                    float other = vals[fr][fn ^ 2][r];  // partner at d +/- 32
                    float rv = vals[fr][fn][r] * cv + ((fn < 2) ? -other : other) * sv;
                    outp[((size_t)(b * HH + h) * NN + n) * DD + d] = f2bf(rv);
                }
            }
    } else {
#pragma unroll
        for (int fr = 0; fr < 2; fr++)
#pragma unroll
            for (int r = 0; r < 4; r++) {
                int m = row0 + w * 32 + fr * 16 + lg * 4 + r;
                int b = m >> 11, n = m & (NN - 1);
#pragma unroll
                for (int fn = 0; fn < 4; fn++) {
                    int d = fn * 16 + ql;
                    // v stored transposed: [b][h][d][n]
                    vws[((size_t)(b * HH + h) * DD + d) * NN + n] = f2bf(vals[fr][fn][r]);
                }
            }
    }
}

// ---------------- Attention (flash, S^T / O^T formulation) ----------------
// grid (16, 24), block 256 (4 waves). Wave owns 32 q; block stages 64-key K/V tiles.
__launch_bounds__(256)
__global__ void k_attn(const unsigned short* __restrict__ qws,
                       const unsigned short* __restrict__ kws,
                       const unsigned short* __restrict__ vws,
                       unsigned short* __restrict__ yws) {
    __shared__ unsigned short Ks[64][72];  // [kk][d]
    __shared__ unsigned short Vs[64][72];  // [d][kk]  (v already transposed in ws)
    const int tid = threadIdx.x;
    const int lane = tid & 63, w = tid >> 6;
    const int ql = lane & 15, lg = lane >> 4;
    const int bh = blockIdx.y;
    const int qw = blockIdx.x * 128 + w * 32;
    const unsigned short* Qp = qws + (size_t)bh * NN * DD;
    const unsigned short* Kp = kws + (size_t)bh * NN * DD;
    const unsigned short* Vp = vws + (size_t)bh * DD * NN;

    // Q fragments hoisted (B-operand of S^T): col q = ql, k = d
    bf16x8 qf[2][2];
#pragma unroll
    for (int fn = 0; fn < 2; fn++)
#pragma unroll
        for (int kb = 0; kb < 2; kb++)
            qf[fn][kb] = ld_frag(Qp + (size_t)(qw + fn * 16 + ql) * DD + kb * 32 + lg * 4);

    f32x4 oacc[4][2];
#pragma unroll
    for (int a = 0; a < 4; a++)
#pragma unroll
        for (int b = 0; b < 2; b++) oacc[a][b] = f32x4{0.f, 0.f, 0.f, 0.f};
    float mrun[2] = {-1e30f, -1e30f}, lrun[2] = {0.f, 0.f};

    const int sr = tid >> 2, sc = (tid & 3) * 16;

    for (int kt = 0; kt < NN / 64; kt++) {
        *(uint4*)&Ks[sr][sc]     = *(const uint4*)(Kp + (size_t)(kt * 64 + sr) * DD + sc);
        *(uint4*)&Ks[sr][sc + 8] = *(const uint4*)(Kp + (size_t)(kt * 64 + sr) * DD + sc + 8);
        *(uint4*)&Vs[sr][sc]     = *(const uint4*)(Vp + (size_t)sr * NN + kt * 64 + sc);
        *(uint4*)&Vs[sr][sc + 8] = *(const uint4*)(Vp + (size_t)sr * NN + kt * 64 + sc + 8);
        __syncthreads();

        // S^T[kk][q] = sum_d K[kk][d] Q[q][d]
        f32x4 sacc[4][2];
#pragma unroll
        for (int a = 0; a < 4; a++)
#pragma unroll
            for (int b = 0; b < 2; b++) sacc[a][b] = f32x4{0.f, 0.f, 0.f, 0.f};
#pragma unroll
        for (int kb = 0; kb < 2; kb++) {
            bf16x8 kf[4];
#pragma unroll
            for (int fr = 0; fr < 4; fr++) kf[fr] = ld_frag(&Ks[fr * 16 + ql][kb * 32 + lg * 4]);
#pragma unroll
            for (int fr = 0; fr < 4; fr++)
#pragma unroll
                for (int fn = 0; fn < 2; fn++)
                    sacc[fr][fn] = __builtin_amdgcn_mfma_f32_16x16x32_bf16(kf[fr], qf[fn][kb], sacc[fr][fn], 0, 0, 0);
        }

        // online softmax per q-column (col q = fn*16+ql, stats in-lane + shfl over lg)
#pragma unroll
        for (int fn = 0; fn < 2; fn++) {
            float tm = -1e30f;
#pragma unroll
            for (int fr = 0; fr < 4; fr++) {
                sacc[fr][fn] *= 0.125f;  // 1/sqrt(64)
#pragma unroll
                for (int r = 0; r < 4; r++) tm = fmaxf(tm, sacc[fr][fn][r]);
            }
            tm = fmaxf(tm, __shfl_xor(tm, 16));
            tm = fmaxf(tm, __shfl_xor(tm, 32));
            float mn = fmaxf(mrun[fn], tm);
            float scl = __expf(mrun[fn] - mn);
            mrun[fn] = mn;
            float ts = 0.f;
#pragma unroll
            for (int fr = 0; fr < 4; fr++)
#pragma unroll
                for (int r = 0; r < 4; r++) {
                    float p = __expf(sacc[fr][fn][r] - mn);
                    sacc[fr][fn][r] = p;
                    ts += p;
                }
            ts += __shfl_xor(ts, 16);
            ts += __shfl_xor(ts, 32);
            lrun[fn] = lrun[fn] * scl + ts;
#pragma unroll
            for (int db = 0; db < 4; db++) oacc[db][fn] *= scl;
        }

        // in-lane repack: S^T C/D frag -> B-operand frags of PV (no cross-lane traffic)
        bf16x8 pB[2][2];
#pragma unroll
        for (int fn = 0; fn < 2; fn++)
#pragma unroll
            for (int kkb = 0; kkb < 2; kkb++) {
                bf16x8 t8;
#pragma unroll
                for (int e = 0; e < 8; e++)
                    t8[e] = (short)f2bf(sacc[kkb * 2 + (e >> 2)][fn][e & 3]);
                pB[fn][kkb] = t8;
            }

        // O^T[d][q] += sum_kk V^T[d][kk] P^T[kk][q]
#pragma unroll
        for (int db = 0; db < 4; db++) {
            bf16x8 va[2];
#pragma unroll
            for (int kkb = 0; kkb < 2; kkb++) va[kkb] = ld_frag(&Vs[db * 16 + ql][kkb * 32 + lg * 4]);
#pragma unroll
            for (int kkb = 0; kkb < 2; kkb++)
#pragma unroll
                for (int fn = 0; fn < 2; fn++)
                    oacc[db][fn] = __builtin_amdgcn_mfma_f32_16x16x32_bf16(va[kkb], pB[fn][kkb], oacc[db][fn], 0, 0, 0);
        }
        __syncthreads();
    }

    // epilogue: O^T frag row = d, col = q; stats per col -> in-lane normalize
    const int b = bh / HH, h = bh % HH;
#pragma unroll
    for (int fn = 0; fn < 2; fn++) {
        float inv = 1.0f / lrun[fn];
        int q = qw + fn * 16 + ql;
#pragma unroll
        for (int db = 0; db < 4; db++)
#pragma unroll
            for (int r = 0; r < 4; r++) {
                int d = db * 16 + lg * 4 + r;
                yws[(size_t)(b * NN + q) * CC + h * DD + d] = f2bf(oacc[db][fn][r] * inv);
            }
    }
}

// ---------------- GEMM2: out = y @ W_out + b_out (f32 out) ----------------
__launch_bounds__(256)
__global__ void k_out(const unsigned short* __restrict__ yb,
                      const unsigned short* __restrict__ wb,
                      const float* __restrict__ bias,
                      float* __restrict__ out) {
    __shared__ unsigned short As[128][40];
    __shared__ unsigned short Bs[64][40];
    const int tid = threadIdx.x;
    const int lane = tid & 63, w = tid >> 6;
    const int ql = lane & 15, lg = lane >> 4;
    const int row0 = blockIdx.x * 128;
    const int j0 = blockIdx.y * 64;

    f32x4 acc[2][4];
#pragma unroll
    for (int a = 0; a < 2; a++)
#pragma unroll
        for (int b = 0; b < 4; b++) acc[a][b] = f32x4{0.f, 0.f, 0.f, 0.f};

    const int ar = tid >> 1, ac = (tid & 1) * 16;
    const int bk = tid >> 3, bc = (tid & 7) * 8;

    for (int k0 = 0; k0 < CC; k0 += 32) {
        uint4 av0 = *(const uint4*)(yb + (size_t)(row0 + ar) * CC + k0 + ac);
        uint4 av1 = *(const uint4*)(yb + (size_t)(row0 + ar) * CC + k0 + ac + 8);
        uint4 bv  = *(const uint4*)(wb + (size_t)(k0 + bk) * CC + j0 + bc);
        *(uint4*)&As[ar][ac]     = av0;
        *(uint4*)&As[ar][ac + 8] = av1;
        const unsigned short* pb = (const unsigned short*)&bv;
#pragma unroll
        for (int i = 0; i < 8; i++) Bs[bc + i][bk] = pb[i];
        __syncthreads();

        bf16x8 af[2], bfr[4];
#pragma unroll
        for (int fr = 0; fr < 2; fr++) af[fr] = ld_frag(&As[w * 32 + fr * 16 + ql][lg * 4]);
#pragma unroll
        for (int fn = 0; fn < 4; fn++) bfr[fn] = ld_frag(&Bs[fn * 16 + ql][lg * 4]);
#pragma unroll
        for (int fr = 0; fr < 2; fr++)
#pragma unroll
            for (int fn = 0; fn < 4; fn++)
                acc[fr][fn] = __builtin_amdgcn_mfma_f32_16x16x32_bf16(af[fr], bfr[fn], acc[fr][fn], 0, 0, 0);
        __syncthreads();
    }

#pragma unroll
    for (int fr = 0; fr < 2; fr++)
#pragma unroll
        for (int fn = 0; fn < 4; fn++) {
            float bj = bias[j0 + fn * 16 + ql];
#pragma unroll
            for (int r = 0; r < 4; r++) {
                int m = row0 + w * 32 + fr * 16 + lg * 4 + r;
                out[(size_t)m * CC + j0 + fn * 16 + ql] = acc[fr][fn][r] + bj;
            }
        }
}

extern "C" void kernel_launch(void* const* d_in, const int* in_sizes, int n_in,
                              void* d_out, int out_size, void* d_ws, size_t ws_size,
                              hipStream_t stream) {
    const float* x    = (const float*)d_in[0];
    const float* sinp = (const float*)d_in[1];
    const float* cosp = (const float*)d_in[2];
    const float* wqkv = (const float*)d_in[3];
    const float* bqkv = (const float*)d_in[4];
    const float* wout = (const float*)d_in[5];
    const float* bout = (const float*)d_in[6];
    float* out = (float*)d_out;
    char* ws = (char*)d_ws;

    unsigned short* xb  = (unsigned short*)(ws);
    unsigned short* wqb = (unsigned short*)(ws + 6291456);
    unsigned short* wob = (unsigned short*)(ws + 9830400);
    unsigned short* qws = (unsigned short*)(ws + 11010048);
    unsigned short* kws = (unsigned short*)(ws + 17301504);
    unsigned short* vws = (unsigned short*)(ws + 23592960);
    unsigned short* yws = (unsigned short*)(ws + 29884416);
    if (ws_size < 36175872) return;  // need ~34.5 MiB scratch

    k_cvt<<<dim3(512), dim3(256), 0, stream>>>(x, xb, MM * CC / 4);
    k_cvt<<<dim3(512), dim3(256), 0, stream>>>(wqkv, wqb, CC * N3 / 4);
    k_cvt<<<dim3(256), dim3(256), 0, stream>>>(wout, wob, CC * CC / 4);
    k_qkv<<<dim3(32, 36), dim3(256), 0, stream>>>(xb, wqb, bqkv, sinp, cosp, qws, kws, vws);
    k_attn<<<dim3(16, 24), dim3(256), 0, stream>>>(qws, kws, vws, yws);
    k_out<<<dim3(32, 12), dim3(256), 0, stream>>>(yws, wob, bout, out);
}

// Round 2
// 142.446 us; speedup vs baseline: 1.3508x; 1.3508x over previous
//
#include <hip/hip_runtime.h>
#include <hip/hip_bf16.h>

#define BB 2
#define NN 2048
#define CC 768
#define HH 12
#define DD 64
#define MM 4096
#define N3 2304

typedef __attribute__((ext_vector_type(8))) short bf16x8;
typedef __attribute__((ext_vector_type(4))) float f32x4;

// 0.125 (1/sqrt(D)) * log2(e) folded into Q so softmax runs in base-2 units
#define QSCALE 0.18033688011112043f

__device__ __forceinline__ unsigned short f2bf(float f) {
    union { float f; unsigned u; } v; v.f = f;
    unsigned r = v.u + 0x7FFFu + ((v.u >> 16) & 1u);
    return (unsigned short)(r >> 16);
}

__device__ __forceinline__ float exp2_hw(float x) {
    float r;
    asm("v_exp_f32 %0, %1" : "=v"(r) : "v"(x));
    return r;
}

// loads elements [0..3] and [16..19] from p (bf16 A/B fragment k-pattern)
__device__ __forceinline__ bf16x8 ld_frag(const unsigned short* p) {
    bf16x8 r;
    __builtin_memcpy(&r, p, 8);
    __builtin_memcpy((char*)&r + 8, p + 16, 8);
    return r;
}

__global__ void k_cvt(const float* __restrict__ s, unsigned short* __restrict__ d, int n4) {
    int i = blockIdx.x * blockDim.x + threadIdx.x;
    int st = gridDim.x * blockDim.x;
    for (; i < n4; i += st) {
        float4 v = ((const float4*)s)[i];
        ushort4 o;
        o.x = f2bf(v.x); o.y = f2bf(v.y); o.z = f2bf(v.z); o.w = f2bf(v.w);
        ((ushort4*)d)[i] = o;
    }
}

// transpose+convert: src f32 [R][Cc] -> dst bf16 [Cc][R]; grid (Cc/64, R/64)
__global__ void k_cvtT(const float* __restrict__ s, unsigned short* __restrict__ d,
                       int R, int Cc) {
    __shared__ unsigned short t[64][72];
    const int c0 = blockIdx.x * 64, r0 = blockIdx.y * 64;
    const int tr = threadIdx.x >> 4;
    const int tc = (threadIdx.x & 15) * 4;
#pragma unroll
    for (int i = 0; i < 4; i++) {
        int r = tr + i * 16;
        float4 v = *(const float4*)(s + (size_t)(r0 + r) * Cc + c0 + tc);
        t[tc + 0][r] = f2bf(v.x);
        t[tc + 1][r] = f2bf(v.y);
        t[tc + 2][r] = f2bf(v.z);
        t[tc + 3][r] = f2bf(v.w);
    }
    __syncthreads();
    const int wr = threadIdx.x >> 2;
    const int wc = (threadIdx.x & 3) * 16;
    *(uint4*)(d + (size_t)(c0 + wr) * R + r0 + wc)     = *(uint4*)&t[wr][wc];
    *(uint4*)(d + (size_t)(c0 + wr) * R + r0 + wc + 8) = *(uint4*)&t[wr][wc + 8];
}

// ---------------- GEMM1: qkv = x @ W_qkv + b, fused RoPE ----------------
// grid (32, 36), block 256. Tile 128(M) x 64(N), BK=32. Wt is [N3][CC] (transposed).
__launch_bounds__(256)
__global__ void k_qkv(const unsigned short* __restrict__ xb,
                      const unsigned short* __restrict__ wt,
                      const float* __restrict__ bias,
                      const float* __restrict__ sinp,
                      const float* __restrict__ cosp,
                      unsigned short* __restrict__ qws,
                      unsigned short* __restrict__ kws,
                      unsigned short* __restrict__ vws) {
    __shared__ unsigned short As[128][40];   // [m][k]
    __shared__ unsigned short Bs[64][40];    // [j][k]
    const int tid = threadIdx.x;
    const int lane = tid & 63, w = tid >> 6;
    const int ql = lane & 15, lg = lane >> 4;
    const int row0 = blockIdx.x * 128;
    const int j0 = blockIdx.y * 64;

    f32x4 acc[2][4];
#pragma unroll
    for (int a = 0; a < 2; a++)
#pragma unroll
        for (int b = 0; b < 4; b++) acc[a][b] = f32x4{0.f, 0.f, 0.f, 0.f};

    const int ar = tid >> 1, ac = (tid & 1) * 16;
    const int jr = tid >> 2, kc = (tid & 3) * 8;

    for (int k0 = 0; k0 < CC; k0 += 32) {
        uint4 av0 = *(const uint4*)(xb + (size_t)(row0 + ar) * CC + k0 + ac);
        uint4 av1 = *(const uint4*)(xb + (size_t)(row0 + ar) * CC + k0 + ac + 8);
        uint4 bv  = *(const uint4*)(wt + (size_t)(j0 + jr) * CC + k0 + kc);
        *(uint4*)&As[ar][ac]     = av0;
        *(uint4*)&As[ar][ac + 8] = av1;
        *(uint4*)&Bs[jr][kc]     = bv;
        __syncthreads();

        bf16x8 af[2], bfr[4];
#pragma unroll
        for (int fr = 0; fr < 2; fr++) af[fr] = ld_frag(&As[w * 32 + fr * 16 + ql][lg * 4]);
#pragma unroll
        for (int fn = 0; fn < 4; fn++) bfr[fn] = ld_frag(&Bs[fn * 16 + ql][lg * 4]);
#pragma unroll
        for (int fr = 0; fr < 2; fr++)
#pragma unroll
            for (int fn = 0; fn < 4; fn++)
                acc[fr][fn] = __builtin_amdgcn_mfma_f32_16x16x32_bf16(af[fr], bfr[fn], acc[fr][fn], 0, 0, 0);
        __syncthreads();
    }

    float vals[2][4][4];
#pragma unroll
    for (int fr = 0; fr < 2; fr++)
#pragma unroll
        for (int fn = 0; fn < 4; fn++) {
            float bj = bias[j0 + fn * 16 + ql];
#pragma unroll
            for (int r = 0; r < 4; r++) vals[fr][fn][r] = acc[fr][fn][r] + bj;
        }
    const int t = j0 / CC;
    const int h = (j0 % CC) >> 6;
    if (t < 2) {
        unsigned short* outp = (t == 0) ? qws : kws;
        const float qs = (t == 0) ? QSCALE : 1.0f;
#pragma unroll
        for (int fr = 0; fr < 2; fr++)
#pragma unroll
            for (int r = 0; r < 4; r++) {
                int m = row0 + w * 32 + fr * 16 + lg * 4 + r;
                int b = m >> 11, n = m & (NN - 1);
#pragma unroll
                for (int fn = 0; fn < 4; fn++) {
                    int d = fn * 16 + ql;
                    float cv = cosp[n * DD + d], sv = sinp[n * DD + d];
                    float other = vals[fr][fn ^ 2][r];  // partner at d +/- 32
                    float rv = (vals[fr][fn][r] * cv + ((fn < 2) ? -other : other) * sv) * qs;
                    outp[((size_t)(b * HH + h) * NN + n) * DD + d] = f2bf(rv);
                }
            }
    } else {
#pragma unroll
        for (int fr = 0; fr < 2; fr++)
#pragma unroll
            for (int r = 0; r < 4; r++) {
                int m = row0 + w * 32 + fr * 16 + lg * 4 + r;
                int b = m >> 11, n = m & (NN - 1);
#pragma unroll
                for (int fn = 0; fn < 4; fn++) {
                    int d = fn * 16 + ql;
                    vws[((size_t)(b * HH + h) * DD + d) * NN + n] = f2bf(vals[fr][fn][r]);
                }
            }
    }
}

// ---------------- Attention (flash, S^T / O^T formulation) ----------------
// grid (32, 24), block 256 (4 waves). Wave owns 16 q; block stages 64-key K/V tiles.
__launch_bounds__(256)
__global__ void k_attn(const unsigned short* __restrict__ qws,
                       const unsigned short* __restrict__ kws,
                       const unsigned short* __restrict__ vws,
                       unsigned short* __restrict__ yws) {
    __shared__ unsigned short Ks[64][72];  // [kk][d]
    __shared__ unsigned short Vs[64][72];  // [d][kk]
    const int tid = threadIdx.x;
    const int lane = tid & 63, w = tid >> 6;
    const int ql = lane & 15, lg = lane >> 4;
    const int bh = blockIdx.y;
    const int qw = blockIdx.x * 64 + w * 16;
    const unsigned short* Qp = qws + (size_t)bh * NN * DD;
    const unsigned short* Kp = kws + (size_t)bh * NN * DD;
    const unsigned short* Vp = vws + (size_t)bh * DD * NN;

    // Q fragments hoisted (B-operand of S^T): col q = ql, k = d (pre-scaled by QSCALE)
    bf16x8 qf[2];
#pragma unroll
    for (int kb = 0; kb < 2; kb++)
        qf[kb] = ld_frag(Qp + (size_t)(qw + ql) * DD + kb * 32 + lg * 4);

    f32x4 oacc[4];
#pragma unroll
    for (int a = 0; a < 4; a++) oacc[a] = f32x4{0.f, 0.f, 0.f, 0.f};
    float mrun = -1e30f, lrun = 0.f;

    const int sr = tid >> 2, sc = (tid & 3) * 16;

    for (int kt = 0; kt < NN / 64; kt++) {
        *(uint4*)&Ks[sr][sc]     = *(const uint4*)(Kp + (size_t)(kt * 64 + sr) * DD + sc);
        *(uint4*)&Ks[sr][sc + 8] = *(const uint4*)(Kp + (size_t)(kt * 64 + sr) * DD + sc + 8);
        *(uint4*)&Vs[sr][sc]     = *(const uint4*)(Vp + (size_t)sr * NN + kt * 64 + sc);
        *(uint4*)&Vs[sr][sc + 8] = *(const uint4*)(Vp + (size_t)sr * NN + kt * 64 + sc + 8);
        __syncthreads();

        // S^T[kk][q] = sum_d K[kk][d] * Qs[q][d]   (already in log2 units)
        f32x4 sacc[4];
#pragma unroll
        for (int a = 0; a < 4; a++) sacc[a] = f32x4{0.f, 0.f, 0.f, 0.f};
        __builtin_amdgcn_s_setprio(1);
#pragma unroll
        for (int kb = 0; kb < 2; kb++) {
            bf16x8 kf[4];
#pragma unroll
            for (int fr = 0; fr < 4; fr++) kf[fr] = ld_frag(&Ks[fr * 16 + ql][kb * 32 + lg * 4]);
#pragma unroll
            for (int fr = 0; fr < 4; fr++)
                sacc[fr] = __builtin_amdgcn_mfma_f32_16x16x32_bf16(kf[fr], qf[kb], sacc[fr], 0, 0, 0);
        }
        __builtin_amdgcn_s_setprio(0);

        // online softmax per q-column (col q = ql, stats in-lane + shfl over lg)
        float m0 = fmaxf(fmaxf(sacc[0][0], sacc[0][1]), fmaxf(sacc[0][2], sacc[0][3]));
        float m1 = fmaxf(fmaxf(sacc[1][0], sacc[1][1]), fmaxf(sacc[1][2], sacc[1][3]));
        float m2 = fmaxf(fmaxf(sacc[2][0], sacc[2][1]), fmaxf(sacc[2][2], sacc[2][3]));
        float m3 = fmaxf(fmaxf(sacc[3][0], sacc[3][1]), fmaxf(sacc[3][2], sacc[3][3]));
        float tm = fmaxf(fmaxf(m0, m1), fmaxf(m2, m3));
        tm = fmaxf(tm, __shfl_xor(tm, 16));
        tm = fmaxf(tm, __shfl_xor(tm, 32));
        // defer-max: only rescale when the running max grows by more than 8 (log2)
        if (__any(tm > mrun + 8.0f)) {
            float mn = fmaxf(mrun, tm);
            float scl = exp2_hw(mrun - mn);
            lrun *= scl;
#pragma unroll
            for (int db = 0; db < 4; db++) oacc[db] *= scl;
            mrun = mn;
        }
        float ts = 0.f;
#pragma unroll
        for (int fr = 0; fr < 4; fr++)
#pragma unroll
            for (int r = 0; r < 4; r++) {
                float p = exp2_hw(sacc[fr][r] - mrun);
                sacc[fr][r] = p;
                ts += p;
            }
        ts += __shfl_xor(ts, 16);
        ts += __shfl_xor(ts, 32);
        lrun += ts;

        // in-lane repack: S^T C/D frag -> B-operand frags of PV
        bf16x8 pB[2];
#pragma unroll
        for (int kkb = 0; kkb < 2; kkb++) {
            bf16x8 t8;
#pragma unroll
            for (int e = 0; e < 8; e++)
                t8[e] = (short)f2bf(sacc[kkb * 2 + (e >> 2)][e & 3]);
            pB[kkb] = t8;
        }

        // O^T[d][q] += sum_kk V^T[d][kk] P^T[kk][q]
        __builtin_amdgcn_s_setprio(1);
#pragma unroll
        for (int db = 0; db < 4; db++) {
            bf16x8 va[2];
#pragma unroll
            for (int kkb = 0; kkb < 2; kkb++) va[kkb] = ld_frag(&Vs[db * 16 + ql][kkb * 32 + lg * 4]);
#pragma unroll
            for (int kkb = 0; kkb < 2; kkb++)
                oacc[db] = __builtin_amdgcn_mfma_f32_16x16x32_bf16(va[kkb], pB[kkb], oacc[db], 0, 0, 0);
        }
        __builtin_amdgcn_s_setprio(0);
        __syncthreads();
    }

    // epilogue: O^T frag row = d, col = q
    const int b = bh / HH, h = bh % HH;
    float inv = 1.0f / lrun;
    int q = qw + ql;
#pragma unroll
    for (int db = 0; db < 4; db++)
#pragma unroll
        for (int r = 0; r < 4; r++) {
            int d = db * 16 + lg * 4 + r;
            yws[(size_t)(b * NN + q) * CC + h * DD + d] = f2bf(oacc[db][r] * inv);
        }
}

// ---------------- GEMM2: out = y @ W_out + b_out (f32 out) ----------------
// Wot is [CC][CC] transposed.
__launch_bounds__(256)
__global__ void k_out(const unsigned short* __restrict__ yb,
                      const unsigned short* __restrict__ wt,
                      const float* __restrict__ bias,
                      float* __restrict__ out) {
    __shared__ unsigned short As[128][40];
    __shared__ unsigned short Bs[64][40];
    const int tid = threadIdx.x;
    const int lane = tid & 63, w = tid >> 6;
    const int ql = lane & 15, lg = lane >> 4;
    const int row0 = blockIdx.x * 128;
    const int j0 = blockIdx.y * 64;

    f32x4 acc[2][4];
#pragma unroll
    for (int a = 0; a < 2; a++)
#pragma unroll
        for (int b = 0; b < 4; b++) acc[a][b] = f32x4{0.f, 0.f, 0.f, 0.f};

    const int ar = tid >> 1, ac = (tid & 1) * 16;
    const int jr = tid >> 2, kc = (tid & 3) * 8;

    for (int k0 = 0; k0 < CC; k0 += 32) {
        uint4 av0 = *(const uint4*)(yb + (size_t)(row0 + ar) * CC + k0 + ac);
        uint4 av1 = *(const uint4*)(yb + (size_t)(row0 + ar) * CC + k0 + ac + 8);
        uint4 bv  = *(const uint4*)(wt + (size_t)(j0 + jr) * CC + k0 + kc);
        *(uint4*)&As[ar][ac]     = av0;
        *(uint4*)&As[ar][ac + 8] = av1;
        *(uint4*)&Bs[jr][kc]     = bv;
        __syncthreads();

        bf16x8 af[2], bfr[4];
#pragma unroll
        for (int fr = 0; fr < 2; fr++) af[fr] = ld_frag(&As[w * 32 + fr * 16 + ql][lg * 4]);
#pragma unroll
        for (int fn = 0; fn < 4; fn++) bfr[fn] = ld_frag(&Bs[fn * 16 + ql][lg * 4]);
#pragma unroll
        for (int fr = 0; fr < 2; fr++)
#pragma unroll
            for (int fn = 0; fn < 4; fn++)
                acc[fr][fn] = __builtin_amdgcn_mfma_f32_16x16x32_bf16(af[fr], bfr[fn], acc[fr][fn], 0, 0, 0);
        __syncthreads();
    }

#pragma unroll
    for (int fr = 0; fr < 2; fr++)
#pragma unroll
        for (int fn = 0; fn < 4; fn++) {
            float bj = bias[j0 + fn * 16 + ql];
#pragma unroll
            for (int r = 0; r < 4; r++) {
                int m = row0 + w * 32 + fr * 16 + lg * 4 + r;
                out[(size_t)m * CC + j0 + fn * 16 + ql] = acc[fr][fn][r] + bj;
            }
        }
}

extern "C" void kernel_launch(void* const* d_in, const int* in_sizes, int n_in,
                              void* d_out, int out_size, void* d_ws, size_t ws_size,
                              hipStream_t stream) {
    const float* x    = (const float*)d_in[0];
    const float* sinp = (const float*)d_in[1];
    const float* cosp = (const float*)d_in[2];
    const float* wqkv = (const float*)d_in[3];
    const float* bqkv = (const float*)d_in[4];
    const float* wout = (const float*)d_in[5];
    const float* bout = (const float*)d_in[6];
    float* out = (float*)d_out;
    char* ws = (char*)d_ws;

    unsigned short* xb  = (unsigned short*)(ws);            // 4096x768 bf16
    unsigned short* wqb = (unsigned short*)(ws + 6291456);  // Wt_qkv [2304][768]
    unsigned short* wob = (unsigned short*)(ws + 9830400);  // Wt_out [768][768]
    unsigned short* qws = (unsigned short*)(ws + 11010048);
    unsigned short* kws = (unsigned short*)(ws + 17301504);
    unsigned short* vws = (unsigned short*)(ws + 23592960);
    unsigned short* yws = (unsigned short*)(ws + 29884416);
    if (ws_size < 36175872) return;

    k_cvt<<<dim3(512), dim3(256), 0, stream>>>(x, xb, MM * CC / 4);
    k_cvtT<<<dim3(36, 12), dim3(256), 0, stream>>>(wqkv, wqb, CC, N3);
    k_cvtT<<<dim3(12, 12), dim3(256), 0, stream>>>(wout, wob, CC, CC);
    k_qkv<<<dim3(32, 36), dim3(256), 0, stream>>>(xb, wqb, bqkv, sinp, cosp, qws, kws, vws);
    k_attn<<<dim3(32, 24), dim3(256), 0, stream>>>(qws, kws, vws, yws);
    k_out<<<dim3(32, 12), dim3(256), 0, stream>>>(yws, wob, bout, out);
}